// Round 11
// baseline (229.637 us; speedup 1.0000x reference)
//
#include <hip/hip_runtime.h>
#include <hip/hip_bf16.h>

typedef __bf16 bf16;
typedef __bf16 bf16x8 __attribute__((ext_vector_type(8)));
typedef __bf16 bf16x4 __attribute__((ext_vector_type(4)));
typedef short s16x4 __attribute__((ext_vector_type(4)));
typedef float f32x4 __attribute__((ext_vector_type(4)));

static __device__ __forceinline__ f32x4 mfma16(bf16x8 a, bf16x8 b, f32x4 c) {
  return __builtin_amdgcn_mfma_f32_16x16x32_bf16(a, b, c, 0, 0, 0);
}

// 16x16x16 bf16 MFMA (K=16). A-frag layout A[row=lane&15][k=4*(lane>>4)+j]
// matches the swapped-QK^T S layout exactly (verified correct in round 8).
static __device__ __forceinline__ f32x4 mfma16k16(bf16x4 a, bf16x4 b, f32x4 c) {
#if __has_builtin(__builtin_amdgcn_mfma_f32_16x16x16bf16_1k)
  return __builtin_amdgcn_mfma_f32_16x16x16bf16_1k(*(s16x4*)&a, *(s16x4*)&b, c, 0, 0, 0);
#else
  asm volatile("v_mfma_f32_16x16x16_bf16 %0, %1, %2, %0" : "+v"(c) : "v"(a), "v"(b));
  return c;
#endif
}

static __device__ __forceinline__ bf16x8 cvt8(const float* p) {
  f32x4 a0 = *(const f32x4*)p;
  f32x4 a1 = *(const f32x4*)(p + 4);
  bf16x8 r;
#pragma unroll
  for (int j = 0; j < 4; ++j) { r[j] = (bf16)a0[j]; r[4 + j] = (bf16)a1[j]; }
  return r;
}

// ---------------------------------------------------------------------------
// prep_wt: W in MFMA B-fragment order (unchanged, proven).
// ---------------------------------------------------------------------------
__global__ void prep_wt(const float* __restrict__ Wq, const float* __restrict__ Wk,
                        const float* __restrict__ Wv, bf16* __restrict__ Wf) {
  int k = blockIdx.x;   // 0..255
  int c = threadIdx.x;  // 0..319
  float v;
  if (c < 32)       v = Wq[k * 32 + c];
  else if (c < 64)  v = Wk[k * 32 + (c - 32)];
  else              v = Wv[k * 256 + (c - 64)];
  int t5 = c >> 6, ct = (c >> 4) & 3, lwc = c & 15;
  int kc = k >> 5, qq = (k >> 3) & 3, ke = k & 7;
  Wf[((((t5 * 8 + kc) * 4 + ct) * 64) + qq * 16 + lwc) * 8 + ke] = (bf16)v;
}

// ---------------------------------------------------------------------------
// qkv_gemm: r5-proven version (unchanged).
// ---------------------------------------------------------------------------
__global__ __launch_bounds__(256) void qkv_gemm(
    const float* __restrict__ x, const bf16* __restrict__ Wf,
    const float* __restrict__ bq, const float* __restrict__ bk,
    const float* __restrict__ bv,
    bf16* __restrict__ Qd, bf16* __restrict__ Kd, bf16* __restrict__ Vt) {
  __shared__ __align__(16) bf16 tile[64 * 72];
  int tid = threadIdx.x;
  int lane = tid & 63, w = tid >> 6;
  int lw = lane & 15, qq = lane >> 4;
  int r0 = blockIdx.x * 64;
  int bb = r0 >> 12, n0 = r0 & 4095;

  const float* arow = x + (size_t)(r0 + 16 * w + lw) * 256;
  bf16x8 a[8];
#pragma unroll
  for (int kc = 0; kc < 8; ++kc) a[kc] = cvt8(arow + kc * 32 + qq * 8);

  for (int c0 = 0; c0 < 320; c0 += 64) {
    int t5 = c0 >> 6;
    f32x4 acc[4] = {};
#pragma unroll
    for (int kc = 0; kc < 8; ++kc)
#pragma unroll
      for (int t = 0; t < 4; ++t) {
        bf16x8 b = *(const bf16x8*)(Wf + ((size_t)(((t5 * 8 + kc) * 4 + t) * 64) + lane) * 8);
        acc[t] = mfma16(a[kc], b, acc[t]);
      }
    if (c0 == 0) {
#pragma unroll
      for (int t = 0; t < 4; ++t) {
        int c = 16 * t + lw;
        float bias = (c < 32) ? bq[c] : bk[c - 32];
#pragma unroll
        for (int i = 0; i < 4; ++i) {
          int n = n0 + 16 * w + 4 * qq + i;
          bf16 hv = (bf16)(acc[t][i] + bias);
          if (c < 32) Qd[((size_t)(bb << 12) + n) * 32 + c] = hv;
          else        Kd[((size_t)(bb << 12) + n) * 32 + (c - 32)] = hv;
        }
      }
    } else {
#pragma unroll
      for (int t = 0; t < 4; ++t) {
        int cl = 16 * t + lw;
        float bias = bv[c0 - 64 + cl];
#pragma unroll
        for (int i = 0; i < 4; ++i)
          tile[cl * 72 + 16 * w + 4 * qq + i] = (bf16)(acc[t][i] + bias);
      }
      __syncthreads();
      int nl = tid & 63;
#pragma unroll
      for (int it = 0; it < 16; ++it) {
        int cl = 4 * it + w;
        Vt[((size_t)bb * 256 + (c0 - 64) + cl) * 4096 + n0 + nl] = tile[cl * 72 + nl];
      }
      __syncthreads();
    }
  }
}

// ---------------------------------------------------------------------------
// flash_attn v11 — kv-split register-P ("r8 done right").
// 8 waves = (kvh in {0,1}) x (cg in {0..3}). Wave: ALL 64 q-rows, 64 channels
// [64cg,+64), kv half [2048*kvh, +2048) in 64 steps of 32 kv.
// Swapped QK (s = mfma(K,Q): lane holds S[kv=16u+4qq+i][q=lw]) -> exp ->
// pack bf16x4 -> directly the A-frag of v_mfma_f32_16x16x16_bf16 for PV.
// NO LDS, NO barriers in the loop; waves free-run (the 85us invariant was
// the phase-locked P-LDS round-trip: r5/r6/r7/r10 all null).
// Traffic per CU per 64 kv: K x4 dup = 32KB, V x1 = 32KB (vs r8's 128KB).
// r8's second bug (compiler sank prefetch loads -> VGPR 60, serialized):
// fixed by the asm memory fence between prefetch-issue and compute.
// Epilogue: cross-kvh o reduction via 65KB LDS, one barrier, kvh=0 writes.
// ---------------------------------------------------------------------------
__global__ __launch_bounds__(512, 2) void flash_attn(
    const bf16* __restrict__ Qd, const bf16* __restrict__ Kd,
    const bf16* __restrict__ Vt, const float* __restrict__ x,
    const float* __restrict__ gamma, float* __restrict__ out) {
  __shared__ float oshare[64 * 260];   // row stride 260 dwords: spreads qq across banks
  __shared__ float lsum[2][64];

  int tid = threadIdx.x;
  int lane = tid & 63, w = tid >> 6;   // w in 0..7
  int lw = lane & 15, qq = lane >> 4;
  int kvh = w >> 2, cg = w & 3, chb = 64 * cg;
  int bb = blockIdx.y;
  int r0 = blockIdx.x * 64;
  int nbase = kvh << 11;               // 0 or 2048

  const bf16* Qb = Qd + ((size_t)bb << 12) * 32;
  const bf16* Kb = Kd + ((size_t)bb << 12) * 32;
  const bf16* Vb = Vt + (size_t)bb * 256 * 4096;

  bf16x8 qf[4];
#pragma unroll
  for (int qt = 0; qt < 4; ++qt)
    qf[qt] = *(const bf16x8*)(Qb + (size_t)(r0 + 16 * qt + lw) * 32 + qq * 8);

  f32x4 o[4][4] = {};                  // [qt][ct]; D row = q offset 4qq+i, col = ch lw
  float l_acc[4] = {};                 // l partial for q = 16qt+lw (this kv half)

  bf16x8 kA[2], kB[2];                 // K[16 kv][32 d] frags (u=0,1)
  bf16x4 vA[8], vB[8];                 // V^T[ch=chb+16ct+lw][kv=16u+4qq..+4], idx ct*2+u

  // ---- prologue: load step 0 ----
#pragma unroll
  for (int u = 0; u < 2; ++u)
    kA[u] = *(const bf16x8*)(Kb + (size_t)(nbase + 16 * u + lw) * 32 + qq * 8);
#pragma unroll
  for (int ct = 0; ct < 4; ++ct)
#pragma unroll
    for (int u = 0; u < 2; ++u)
      vA[ct * 2 + u] = *(const bf16x4*)(Vb + (size_t)(chb + 16 * ct + lw) * 4096 + nbase + 16 * u + 4 * qq);
  asm volatile("" ::: "memory");

  // STEP: prefetch kv-chunk at NNXT into KN/VN; compute from KC/VC.
#define FA_STEP(NNXT, KC, KN, VC, VN)                                              \
  {                                                                                \
    _Pragma("unroll") for (int u = 0; u < 2; ++u)                                  \
      KN[u] = *(const bf16x8*)(Kb + (size_t)((NNXT) + 16 * u + lw) * 32 + qq * 8); \
    _Pragma("unroll") for (int ct = 0; ct < 4; ++ct)                               \
      _Pragma("unroll") for (int u = 0; u < 2; ++u)                                \
        VN[ct * 2 + u] = *(const bf16x4*)(Vb + (size_t)(chb + 16 * ct + lw) * 4096 + (NNXT) + 16 * u + 4 * qq); \
    asm volatile("" ::: "memory");                                                 \
    _Pragma("unroll") for (int u = 0; u < 2; ++u) {                                \
      f32x4 z = {};                                                                \
      f32x4 s0 = mfma16(KC[u], qf[0], z);                                          \
      f32x4 s1 = mfma16(KC[u], qf[1], z);                                          \
      f32x4 s2 = mfma16(KC[u], qf[2], z);                                          \
      f32x4 s3 = mfma16(KC[u], qf[3], z);                                          \
      bf16x4 pa0, pa1, pa2, pa3;                                                   \
      _Pragma("unroll") for (int i = 0; i < 4; ++i) {                              \
        float p;                                                                   \
        p = __expf(s0[i]); l_acc[0] += p; pa0[i] = (bf16)p;                        \
        p = __expf(s1[i]); l_acc[1] += p; pa1[i] = (bf16)p;                        \
        p = __expf(s2[i]); l_acc[2] += p; pa2[i] = (bf16)p;                        \
        p = __expf(s3[i]); l_acc[3] += p; pa3[i] = (bf16)p;                        \
      }                                                                            \
      _Pragma("unroll") for (int ct = 0; ct < 4; ++ct) {                           \
        o[0][ct] = mfma16k16(pa0, VC[ct * 2 + u], o[0][ct]);                       \
        o[1][ct] = mfma16k16(pa1, VC[ct * 2 + u], o[1][ct]);                       \
        o[2][ct] = mfma16k16(pa2, VC[ct * 2 + u], o[2][ct]);                       \
        o[3][ct] = mfma16k16(pa3, VC[ct * 2 + u], o[3][ct]);                       \
      }                                                                            \
    }                                                                              \
  }

  for (int j = 0; j < 64; j += 2) {
    int n1 = nbase + (((j + 1) & 63) << 5);
    int n2 = nbase + (((j + 2) & 63) << 5);
    FA_STEP(n1, kA, kB, vA, vB)
    FA_STEP(n2, kB, kA, vB, vA)
  }
#undef FA_STEP

  // ---- l: sum over qq lane groups (kv within step), store per-half ----
#pragma unroll
  for (int qt = 0; qt < 4; ++qt) {
    l_acc[qt] += __shfl_xor(l_acc[qt], 16);
    l_acc[qt] += __shfl_xor(l_acc[qt], 32);
  }
  if (cg == 0 && qq == 0) {
#pragma unroll
    for (int qt = 0; qt < 4; ++qt) lsum[kvh][16 * qt + lw] = l_acc[qt];
  }

  // ---- cross-kvh o reduction ----
  if (kvh) {
#pragma unroll
    for (int qt = 0; qt < 4; ++qt)
#pragma unroll
      for (int ct = 0; ct < 4; ++ct)
#pragma unroll
        for (int i = 0; i < 4; ++i)
          oshare[(16 * qt + 4 * qq + i) * 260 + chb + 16 * ct + lw] = o[qt][ct][i];
  }
  __syncthreads();

  if (!kvh) {
    float g = gamma[0];
#pragma unroll
    for (int qt = 0; qt < 4; ++qt) {
      f32x4 la = *(const f32x4*)&lsum[0][16 * qt + 4 * qq];
      f32x4 lb = *(const f32x4*)&lsum[1][16 * qt + 4 * qq];
#pragma unroll
      for (int i = 0; i < 4; ++i) {
        float rinv = 1.f / (la[i] + lb[i]);
        int row = r0 + 16 * qt + 4 * qq + i;
        size_t base = (((size_t)bb << 12) + row) * 256 + chb;
#pragma unroll
        for (int ct = 0; ct < 4; ++ct) {
          float osum = o[qt][ct][i] + oshare[(16 * qt + 4 * qq + i) * 260 + chb + 16 * ct + lw];
          out[base + 16 * ct + lw] = g * (osum * rinv) + x[base + 16 * ct + lw];
        }
      }
    }
  }
}

extern "C" void kernel_launch(void* const* d_in, const int* in_sizes, int n_in,
                              void* d_out, int out_size, void* d_ws, size_t ws_size,
                              hipStream_t stream) {
  const float* x     = (const float*)d_in[0];
  const float* Wq    = (const float*)d_in[1];
  const float* bq    = (const float*)d_in[2];
  const float* Wk    = (const float*)d_in[3];
  const float* bk    = (const float*)d_in[4];
  const float* Wv    = (const float*)d_in[5];
  const float* bv    = (const float*)d_in[6];
  const float* gamma = (const float*)d_in[7];
  float* out = (float*)d_out;

  const size_t WT_E = 320 * 256;
  const size_t QK_E = (size_t)4096 * 32;
  const size_t VT_E = (size_t)256 * 4096;
  size_t full_bytes = (WT_E + 4 * 2 * QK_E + 4 * VT_E) * sizeof(bf16);

  bf16* Wf = (bf16*)d_ws;
  prep_wt<<<dim3(256), dim3(320), 0, stream>>>(Wq, Wk, Wv, Wf);

  if (ws_size >= full_bytes) {
    bf16* Qd = Wf + WT_E;
    bf16* Kd = Qd + 4 * QK_E;
    bf16* Vt = Kd + 4 * QK_E;
    qkv_gemm<<<dim3(256), dim3(256), 0, stream>>>(x, Wf, bq, bk, bv, Qd, Kd, Vt);
    flash_attn<<<dim3(64, 4), dim3(512), 0, stream>>>(Qd, Kd, Vt, x, gamma, out);
  } else {
    bf16* Qd = Wf + WT_E;
    bf16* Kd = Qd + QK_E;
    bf16* Vt = Kd + QK_E;
    for (int b = 0; b < 4; ++b) {
      const float* xb = x + (size_t)b * 4096 * 256;
      float* outb = out + (size_t)b * 4096 * 256;
      qkv_gemm<<<dim3(64), dim3(256), 0, stream>>>(xb, Wf, bq, bk, bv, Qd, Kd, Vt);
      flash_attn<<<dim3(64, 1), dim3(512), 0, stream>>>(Qd, Kd, Vt, xb, gamma, outb);
    }
  }
}

// Round 12
// 159.318 us; speedup vs baseline: 1.4414x; 1.4414x over previous
//
#include <hip/hip_runtime.h>
#include <hip/hip_bf16.h>

typedef __bf16 bf16;
typedef __bf16 bf16x8 __attribute__((ext_vector_type(8)));
typedef __bf16 bf16x4 __attribute__((ext_vector_type(4)));
typedef float f32x4 __attribute__((ext_vector_type(4)));

static __device__ __forceinline__ f32x4 mfma16(bf16x8 a, bf16x8 b, f32x4 c) {
  return __builtin_amdgcn_mfma_f32_16x16x32_bf16(a, b, c, 0, 0, 0);
}

// No-drain workgroup barrier: waits only LDS ops, leaves global loads in
// flight (r5-proven correct).
static __device__ __forceinline__ void wg_barrier() {
  asm volatile("s_waitcnt lgkmcnt(0)" ::: "memory");
  __builtin_amdgcn_s_barrier();
  asm volatile("" ::: "memory");
}

static __device__ __forceinline__ bf16x8 cvt8(const float* p) {
  f32x4 a0 = *(const f32x4*)p;
  f32x4 a1 = *(const f32x4*)(p + 4);
  bf16x8 r;
#pragma unroll
  for (int j = 0; j < 4; ++j) { r[j] = (bf16)a0[j]; r[4 + j] = (bf16)a1[j]; }
  return r;
}

// ---------------------------------------------------------------------------
// prep_wt: W in MFMA B-fragment order (unchanged, proven).
// ---------------------------------------------------------------------------
__global__ void prep_wt(const float* __restrict__ Wq, const float* __restrict__ Wk,
                        const float* __restrict__ Wv, bf16* __restrict__ Wf) {
  int k = blockIdx.x;   // 0..255
  int c = threadIdx.x;  // 0..319
  float v;
  if (c < 32)       v = Wq[k * 32 + c];
  else if (c < 64)  v = Wk[k * 32 + (c - 32)];
  else              v = Wv[k * 256 + (c - 64)];
  int t5 = c >> 6, ct = (c >> 4) & 3, lwc = c & 15;
  int kc = k >> 5, qq = (k >> 3) & 3, ke = k & 7;
  Wf[((((t5 * 8 + kc) * 4 + ct) * 64) + qq * 16 + lwc) * 8 + ke] = (bf16)v;
}

// ---------------------------------------------------------------------------
// qkv_gemm: r5-proven version (unchanged).
// ---------------------------------------------------------------------------
__global__ __launch_bounds__(256) void qkv_gemm(
    const float* __restrict__ x, const bf16* __restrict__ Wf,
    const float* __restrict__ bq, const float* __restrict__ bk,
    const float* __restrict__ bv,
    bf16* __restrict__ Qd, bf16* __restrict__ Kd, bf16* __restrict__ Vt) {
  __shared__ __align__(16) bf16 tile[64 * 72];
  int tid = threadIdx.x;
  int lane = tid & 63, w = tid >> 6;
  int lw = lane & 15, qq = lane >> 4;
  int r0 = blockIdx.x * 64;
  int bb = r0 >> 12, n0 = r0 & 4095;

  const float* arow = x + (size_t)(r0 + 16 * w + lw) * 256;
  bf16x8 a[8];
#pragma unroll
  for (int kc = 0; kc < 8; ++kc) a[kc] = cvt8(arow + kc * 32 + qq * 8);

  for (int c0 = 0; c0 < 320; c0 += 64) {
    int t5 = c0 >> 6;
    f32x4 acc[4] = {};
#pragma unroll
    for (int kc = 0; kc < 8; ++kc)
#pragma unroll
      for (int t = 0; t < 4; ++t) {
        bf16x8 b = *(const bf16x8*)(Wf + ((size_t)(((t5 * 8 + kc) * 4 + t) * 64) + lane) * 8);
        acc[t] = mfma16(a[kc], b, acc[t]);
      }
    if (c0 == 0) {
#pragma unroll
      for (int t = 0; t < 4; ++t) {
        int c = 16 * t + lw;
        float bias = (c < 32) ? bq[c] : bk[c - 32];
#pragma unroll
        for (int i = 0; i < 4; ++i) {
          int n = n0 + 16 * w + 4 * qq + i;
          bf16 hv = (bf16)(acc[t][i] + bias);
          if (c < 32) Qd[((size_t)(bb << 12) + n) * 32 + c] = hv;
          else        Kd[((size_t)(bb << 12) + n) * 32 + (c - 32)] = hv;
        }
      }
    } else {
#pragma unroll
      for (int t = 0; t < 4; ++t) {
        int cl = 16 * t + lw;
        float bias = bv[c0 - 64 + cl];
#pragma unroll
        for (int i = 0; i < 4; ++i)
          tile[cl * 72 + 16 * w + 4 * qq + i] = (bf16)(acc[t][i] + bias);
      }
      __syncthreads();
      int nl = tid & 63;
#pragma unroll
      for (int it = 0; it < 16; ++it) {
        int cl = 4 * it + w;
        Vt[((size_t)bb * 256 + (c0 - 64) + cl) * 4096 + n0 + nl] = tile[cl * 72 + nl];
      }
      __syncthreads();
    }
  }
}

// ---------------------------------------------------------------------------
// flash_attn v12 — producer/consumer wave specialization.
// 8 waves: w<4 PRODUCERS, w>=4 CONSUMERS. Zero work duplication (K x1, V x1,
// exp x1), P LDS reads HALVED (4 readers), and — the point — producer's
// QK/exp/P-write of tile j+1 OVERLAPS consumer's P-read/PV of tile j.
// Phase time = max(producer, consumer) instead of their sum (r0's serial
// chain at 3190 cyc/tile was the 85us invariant; r5/r6/r7/r10 nulls proved
// no scheduling trick fixes it without role separation).
//
// Producer w: owns kv-sub [16w,16w+16) of each 64-kv tile, all 64 q rows.
//   Swapped QK (verified r10/r11): s = mfma16(K_frag, Q_frag[qt]) -> lane
//   (qq,lw) holds S[kv=16w+4qq+i][q=16qt+lw] -> exp -> ONE b64 write per qt
//   into Pl[q][kv] (stride 72). l_part[qt] per lane for q=16qt+lw.
// Consumer w: owns ch [64(w-4),+64); reads af (r0-proven b128 pattern),
//   loads V (r0-proven pattern), 32 PV mfma into o[4][4].
// Barriers: 1 per phase, executed by both roles (wave-uniform divergence;
// s_barrier counts wave arrivals, program point irrelevant). 66 each.
// ---------------------------------------------------------------------------
__global__ __launch_bounds__(512, 2) void flash_attn(
    const bf16* __restrict__ Qd, const bf16* __restrict__ Kd,
    const bf16* __restrict__ Vt, const float* __restrict__ x,
    const float* __restrict__ gamma, float* __restrict__ out) {
  __shared__ __align__(16) bf16 Pl[2][64 * 72];
  __shared__ float lsum[4][64];

  int tid = threadIdx.x;
  int lane = tid & 63, w = tid >> 6;
  int lw = lane & 15, qq = lane >> 4;
  int bb = blockIdx.y;
  int r0 = blockIdx.x * 64;

  const bf16* Qb = Qd + ((size_t)bb << 12) * 32;
  const bf16* Kb = Kd + ((size_t)bb << 12) * 32;
  const bf16* Vb = Vt + (size_t)bb * 256 * 4096;

  if (w < 4) {
    // ========================= PRODUCER =========================
    int kvs = 16 * w;
    bf16x8 qfp[4];
#pragma unroll
    for (int qt = 0; qt < 4; ++qt)
      qfp[qt] = *(const bf16x8*)(Qb + (size_t)(r0 + 16 * qt + lw) * 32 + qq * 8);
    float l_part[4] = {};
    bf16x8 kA, kB;

    // prologue: S(0) -> Pl[0] using K(0); prefetch K(1)
    kA = *(const bf16x8*)(Kb + (size_t)(kvs + lw) * 32 + qq * 8);
#pragma unroll
    for (int qt = 0; qt < 4; ++qt) {
      f32x4 z = {};
      f32x4 s = mfma16(kA, qfp[qt], z);
      bf16x4 pk;
#pragma unroll
      for (int i = 0; i < 4; ++i) { float p = __expf(s[i]); l_part[qt] += p; pk[i] = (bf16)p; }
      *(bf16x4*)&Pl[0][(16 * qt + lw) * 72 + kvs + 4 * qq] = pk;
    }
    kB = *(const bf16x8*)(Kb + (size_t)(64 + kvs + lw) * 32 + qq * 8);
    wg_barrier();

    // phase j: compute S(j+1) with KC=K(j+1) -> Pl[(j+1)&1]; load K(j+2)->KN
#define PROD_PH(J, PN, KC, KN)                                                 \
    {                                                                          \
      const int j = (J);                                                       \
      if (j < 63) {                                                            \
        _Pragma("unroll") for (int qt = 0; qt < 4; ++qt) {                     \
          f32x4 z = {};                                                        \
          f32x4 s = mfma16(KC, qfp[qt], z);                                    \
          bf16x4 pk;                                                           \
          _Pragma("unroll") for (int i = 0; i < 4; ++i) {                      \
            float p = __expf(s[i]); l_part[qt] += p; pk[i] = (bf16)p;          \
          }                                                                    \
          *(bf16x4*)&Pl[PN][(16 * qt + lw) * 72 + kvs + 4 * qq] = pk;          \
        }                                                                      \
        int n2 = ((j + 2) & 63) * 64;                                          \
        KN = *(const bf16x8*)(Kb + (size_t)(n2 + kvs + lw) * 32 + qq * 8);     \
      }                                                                        \
      wg_barrier();                                                            \
    }

    for (int jj = 0; jj < 32; ++jj) {
      PROD_PH(2 * jj,     1, kB, kA)
      PROD_PH(2 * jj + 1, 0, kA, kB)
    }
#undef PROD_PH

    // l: reduce over qq groups (kv within sub); each producer owns disjoint kv
#pragma unroll
    for (int qt = 0; qt < 4; ++qt) {
      float v = l_part[qt];
      v += __shfl_xor(v, 16);
      v += __shfl_xor(v, 32);
      if (qq == 0) lsum[w][16 * qt + lw] = v;
    }
    __syncthreads();
  } else {
    // ========================= CONSUMER =========================
    int chb = 64 * (w - 4);
    f32x4 o[4][4] = {};
    bf16x8 vA[8], vB[8];
#pragma unroll
    for (int t = 0; t < 4; ++t)
#pragma unroll
      for (int kc = 0; kc < 2; ++kc)
        vA[t * 2 + kc] = *(const bf16x8*)(Vb + (size_t)(chb + 16 * t + lw) * 4096 + kc * 32 + qq * 8);
    wg_barrier();

    // phase j: PV(j) from Pl[j&1] and VC=V(j); load V(j+1)->VN
#define CONS_PH(J, PC, VC, VN)                                                 \
    {                                                                          \
      const int j = (J);                                                       \
      int n1 = ((j + 1) & 63) * 64;                                            \
      bf16x8 af[4][2];                                                         \
      _Pragma("unroll") for (int m = 0; m < 4; ++m)                            \
        _Pragma("unroll") for (int kc = 0; kc < 2; ++kc)                       \
          af[m][kc] = *(const bf16x8*)&Pl[PC][(16 * m + lw) * 72 + kc * 32 + qq * 8]; \
      _Pragma("unroll") for (int t = 0; t < 4; ++t)                            \
        _Pragma("unroll") for (int kc = 0; kc < 2; ++kc)                       \
          VN[t * 2 + kc] = *(const bf16x8*)(Vb + (size_t)(chb + 16 * t + lw) * 4096 + n1 + kc * 32 + qq * 8); \
      _Pragma("unroll") for (int kc = 0; kc < 2; ++kc)                         \
        _Pragma("unroll") for (int t = 0; t < 4; ++t)                          \
          _Pragma("unroll") for (int m = 0; m < 4; ++m)                        \
            o[m][t] = mfma16(af[m][kc], VC[t * 2 + kc], o[m][t]);              \
      wg_barrier();                                                            \
    }

    for (int jj = 0; jj < 32; ++jj) {
      CONS_PH(2 * jj,     0, vA, vB)
      CONS_PH(2 * jj + 1, 1, vB, vA)
    }
#undef CONS_PH

    __syncthreads();   // producers' lsum now visible

    float g = gamma[0];
#pragma unroll
    for (int m = 0; m < 4; ++m) {
      f32x4 l0 = *(const f32x4*)&lsum[0][16 * m + 4 * qq];
      f32x4 l1 = *(const f32x4*)&lsum[1][16 * m + 4 * qq];
      f32x4 l2 = *(const f32x4*)&lsum[2][16 * m + 4 * qq];
      f32x4 l3 = *(const f32x4*)&lsum[3][16 * m + 4 * qq];
#pragma unroll
      for (int i = 0; i < 4; ++i) {
        float rinv = 1.f / (l0[i] + l1[i] + l2[i] + l3[i]);
        int row = r0 + 16 * m + 4 * qq + i;
        size_t base = (((size_t)bb << 12) + row) * 256 + chb;
#pragma unroll
        for (int t = 0; t < 4; ++t)
          out[base + 16 * t + lw] = g * (o[m][t][i] * rinv) + x[base + 16 * t + lw];
      }
    }
  }
}

extern "C" void kernel_launch(void* const* d_in, const int* in_sizes, int n_in,
                              void* d_out, int out_size, void* d_ws, size_t ws_size,
                              hipStream_t stream) {
  const float* x     = (const float*)d_in[0];
  const float* Wq    = (const float*)d_in[1];
  const float* bq    = (const float*)d_in[2];
  const float* Wk    = (const float*)d_in[3];
  const float* bk    = (const float*)d_in[4];
  const float* Wv    = (const float*)d_in[5];
  const float* bv    = (const float*)d_in[6];
  const float* gamma = (const float*)d_in[7];
  float* out = (float*)d_out;

  const size_t WT_E = 320 * 256;
  const size_t QK_E = (size_t)4096 * 32;
  const size_t VT_E = (size_t)256 * 4096;
  size_t full_bytes = (WT_E + 4 * 2 * QK_E + 4 * VT_E) * sizeof(bf16);

  bf16* Wf = (bf16*)d_ws;
  prep_wt<<<dim3(256), dim3(320), 0, stream>>>(Wq, Wk, Wv, Wf);

  if (ws_size >= full_bytes) {
    bf16* Qd = Wf + WT_E;
    bf16* Kd = Qd + 4 * QK_E;
    bf16* Vt = Kd + 4 * QK_E;
    qkv_gemm<<<dim3(256), dim3(256), 0, stream>>>(x, Wf, bq, bk, bv, Qd, Kd, Vt);
    flash_attn<<<dim3(64, 4), dim3(512), 0, stream>>>(Qd, Kd, Vt, x, gamma, out);
  } else {
    bf16* Qd = Wf + WT_E;
    bf16* Kd = Qd + QK_E;
    bf16* Vt = Kd + QK_E;
    for (int b = 0; b < 4; ++b) {
      const float* xb = x + (size_t)b * 4096 * 256;
      float* outb = out + (size_t)b * 4096 * 256;
      qkv_gemm<<<dim3(64), dim3(256), 0, stream>>>(xb, Wf, bq, bk, bv, Qd, Kd, Vt);
      flash_attn<<<dim3(64, 1), dim3(512), 0, stream>>>(Qd, Kd, Vt, xb, gamma, outb);
    }
  }
}